// Round 8
// baseline (746.112 us; speedup 1.0000x reference)
//
#include <hip/hip_runtime.h>
#include <math.h>

typedef unsigned short u16;
typedef __attribute__((ext_vector_type(8))) short short8;
typedef __attribute__((ext_vector_type(8))) short bf16x8;
typedef __attribute__((ext_vector_type(4))) unsigned short us4;
typedef __attribute__((ext_vector_type(2))) unsigned short us2;
typedef __attribute__((ext_vector_type(8))) unsigned short us8;
typedef __attribute__((ext_vector_type(4))) float f32x4;

#define NP (512*512)
#define MFMA16 __builtin_amdgcn_mfma_f32_16x16x32_bf16

// ---- workspace byte offsets (all 256-aligned) ----
#define TWH   0u
#define TWL   49152u
#define T2H   98304u
#define T2L   163840u
#define THC2H 229376u
#define THC2L 278528u
#define THS2H 327680u
#define THS2L 376832u
#define THCAH 425984u
#define THCAL 491520u
#define THSAH 557056u
#define THSAL 622592u
#define THSNH 688128u
#define THSNL 753664u
#define CFH   819200u
#define CFL   851968u
#define F1H   884736u
#define F1L   901120u
#define XWH   917504u
#define XWL   4063232u
#define XFP   7208960u
#define YPART 8028160u
#define YRH   8847360u
#define YRL   9011200u
#define YIH   9175040u
#define YIL   9338880u
#define ZH    9502720u
#define ZL    13697024u
#define VH    17891328u
#define VL    51445760u

__device__ __forceinline__ u16 brnd(float x){
    unsigned u = __float_as_uint(x);
    unsigned r = (u + 0x7FFFu + ((u>>16)&1u)) >> 16;
    return (u16)r;
}
__device__ __forceinline__ float fbf(u16 h){ return __uint_as_float(((unsigned)h)<<16); }
__device__ __forceinline__ void bsplit(float x, u16& h, u16& l){
    h = brnd(x); l = brnd(x - fbf(h));
}
__device__ __forceinline__ float tanhfast(float x){
    x = fminf(10.f, fmaxf(-10.f, x));
    float e = __expf(2.f*x);
    return (e-1.f)/(e+1.f);
}

// ================= setup: tables + weight frags =================
__global__ void k_setup(char* wsb, const float* __restrict__ convw, const float* __restrict__ fc1w){
    int i = blockIdx.x*256 + threadIdx.x;
    const float c2pi = 6.283185307179586f/512.0f;
    if (i < 24576){                         // TW
        int e=i&7, lane=(i>>3)&63, g=i>>9; int nt=g%3;
        int k = (g/3)*32 + ((lane>>4)<<3) + e;
        int n = nt*16 + (lane&15);
        float v=0.f;
        if(n<40){int kx=n>>1; float a=c2pi*(float)((kx*k)&511); v=(n&1)?-sinf(a):cosf(a);}
        u16 h,l; bsplit(v,h,l);
        ((u16*)(wsb+TWH))[i]=h; ((u16*)(wsb+TWL))[i]=l;
    } else if (i < 57344){                  // T2
        int j2=i-24576;
        int e=j2&7, lane=(j2>>3)&63, g=j2>>9; int ks=g&1, wt=g>>1;
        int j = ks*32 + ((lane>>4)<<3) + e;
        int w = wt*16 + (lane&15);
        float v=0.f;
        if(j<40){int kx=j>>1; float a=c2pi*(float)((kx*w)&511); v=(j&1)?-sinf(a):cosf(a);}
        u16 h,l; bsplit(v,h,l);
        ((u16*)(wsb+T2H))[j2]=h; ((u16*)(wsb+T2L))[j2]=l;
    } else if (i < 81920){                  // f2 A [m48][h512]
        int j2 = i-57344;
        int m=j2>>9, hh=j2&511;
        float vc=0.f,vs=0.f;
        if(m<40){int ky=(m<20)?m:(472+m); float a=c2pi*(float)((ky*hh)&511); vc=cosf(a); vs=sinf(a);}
        u16 h,l;
        bsplit(vc,h,l); ((u16*)(wsb+THC2H))[j2]=h; ((u16*)(wsb+THC2L))[j2]=l;
        bsplit(vs,h,l); ((u16*)(wsb+THS2H))[j2]=h; ((u16*)(wsb+THS2L))[j2]=l;
    } else if (i < 114688){                 // i1 A [h512][m64]
        int j2 = i-81920;
        int hh=j2>>6, m=j2&63;
        float vc=0.f,vs=0.f;
        if(m<40){int ky=(m<20)?m:(472+m); float a=c2pi*(float)((ky*hh)&511); vc=cosf(a); vs=sinf(a);}
        u16 h,l;
        bsplit(vc,h,l);  ((u16*)(wsb+THCAH))[j2]=h; ((u16*)(wsb+THCAL))[j2]=l;
        bsplit(vs,h,l);  ((u16*)(wsb+THSAH))[j2]=h; ((u16*)(wsb+THSAL))[j2]=l;
        bsplit(-vs,h,l); ((u16*)(wsb+THSNH))[j2]=h; ((u16*)(wsb+THSNL))[j2]=l;
    } else {                                // weight frags
        int j = i - 114688;
        if (j < 16384){
            int e=j&7, lane=(j>>3)&63, g=j>>9;
            int mt=g&3, ks=(g>>2)&1, L=g>>3;
            int o = mt*16+(lane&15), c = ks*32+((lane>>4)<<3)+e;
            float v = convw[L*4096 + o*64 + c];
            u16 h,l; bsplit(v,h,l);
            ((u16*)(wsb+CFH))[j]=h; ((u16*)(wsb+CFL))[j]=l;
        } else {
            int j2=j-16384;
            int e=j2&7, lane=(j2>>3)&63, g=j2>>9;
            int mt=g&7, ks=g>>3;
            int f = mt*16+(lane&15), c = ks*32+((lane>>4)<<3)+e;
            float v = fc1w[f*64+c];
            u16 h,l; bsplit(v,h,l);
            ((u16*)(wsb+F1H))[j2]=h; ((u16*)(wsb+F1L))[j2]=l;
        }
    }
}

// ================= fc0 =================
__global__ __launch_bounds__(256) void k_fc0(const float* __restrict__ x,
    const float* __restrict__ w, const float* __restrict__ b,
    u16* __restrict__ vh, u16* __restrict__ vl){
    __shared__ float xs[1024*3];
    __shared__ float ws3[192], bs[64];
    int t = threadIdx.x;
    size_t pb = (size_t)blockIdx.x*1024;
    const float4* xg = (const float4*)(x + pb*3);
    float4* xs4 = (float4*)xs;
    #pragma unroll
    for (int k=0;k<3;k++) xs4[t + k*256] = xg[t + k*256];
    if (t<192) ws3[t]=w[t];
    if (t<64) bs[t]=b[t];
    __syncthreads();
    int p0 = t*4;
    float X0[4],X1[4],X2[4];
    #pragma unroll
    for(int e=0;e<4;e++){X0[e]=xs[(p0+e)*3];X1[e]=xs[(p0+e)*3+1];X2[e]=xs[(p0+e)*3+2];}
    for (int c=0;c<64;c++){
        float w0=ws3[c*3],w1=ws3[c*3+1],w2=ws3[c*3+2],bc=bs[c];
        us4 sh, sl;
        #pragma unroll
        for(int e=0;e<4;e++){
            float v = w0*X0[e]+w1*X1[e]+w2*X2[e]+bc;
            u16 hh,ll; bsplit(v,hh,ll); sh[e]=hh; sl[e]=ll;
        }
        *(us4*)(vh + (size_t)c*NP + pb + p0) = sh;
        *(us4*)(vl + (size_t)c*NP + pb + p0) = sl;
    }
}

// ================= F1: 2 row-tiles per wave, shared B, XCD swizzle =================
__global__ __launch_bounds__(256) void k_f1(const u16* __restrict__ vh, const u16* __restrict__ vl,
    const u16* __restrict__ twh, const u16* __restrict__ twl,
    u16* __restrict__ xwh, u16* __restrict__ xwl){
    int bid = ((blockIdx.x & 7) << 5) | (blockIdx.x >> 3);   // 256 = 8*32 chunked
    int lane = threadIdx.x & 63, wv = threadIdx.x >> 6;
    int r0a = bid*128 + wv*16;
    int r1a = r0a + 64;
    int rl = lane&15;
    const u16* ah0 = vh + (size_t)(r0a+rl)*512 + ((lane>>4)<<3);
    const u16* al0 = vl + (size_t)(r0a+rl)*512 + ((lane>>4)<<3);
    const u16* ah1 = vh + (size_t)(r1a+rl)*512 + ((lane>>4)<<3);
    const u16* al1 = vl + (size_t)(r1a+rl)*512 + ((lane>>4)<<3);
    f32x4 acc[2][3];
    #pragma unroll
    for (int tt = 0; tt < 2; ++tt)
        #pragma unroll
        for (int nt = 0; nt < 3; ++nt) acc[tt][nt] = (f32x4){0.f,0.f,0.f,0.f};
    #pragma unroll 2
    for (int kk = 0; kk < 16; ++kk){
        bf16x8 Bh[3], Bl[3];
        #pragma unroll
        for (int nt = 0; nt < 3; ++nt){
            size_t bo = ((size_t)(kk*3+nt)*64 + lane)*8;
            Bh[nt] = *reinterpret_cast<const bf16x8*>(twh + bo);
            Bl[nt] = *reinterpret_cast<const bf16x8*>(twl + bo);
        }
        bf16x8 Ah0 = *reinterpret_cast<const bf16x8*>(ah0 + kk*32);
        bf16x8 Al0 = *reinterpret_cast<const bf16x8*>(al0 + kk*32);
        bf16x8 Ah1 = *reinterpret_cast<const bf16x8*>(ah1 + kk*32);
        bf16x8 Al1 = *reinterpret_cast<const bf16x8*>(al1 + kk*32);
        #pragma unroll
        for (int nt = 0; nt < 3; ++nt){
            acc[0][nt] = MFMA16(Ah0, Bh[nt], acc[0][nt], 0,0,0);
            acc[0][nt] = MFMA16(Ah0, Bl[nt], acc[0][nt], 0,0,0);
            acc[0][nt] = MFMA16(Al0, Bh[nt], acc[0][nt], 0,0,0);
            acc[1][nt] = MFMA16(Ah1, Bh[nt], acc[1][nt], 0,0,0);
            acc[1][nt] = MFMA16(Ah1, Bl[nt], acc[1][nt], 0,0,0);
            acc[1][nt] = MFMA16(Al1, Bh[nt], acc[1][nt], 0,0,0);
        }
    }
    int colj = lane&15;
    #pragma unroll
    for (int tt = 0; tt < 2; ++tt){
        int r0 = (tt ? r1a : r0a) + ((lane>>4)<<2);
        int c = r0>>9, h0 = r0&511;
        #pragma unroll
        for (int nt = 0; nt < 3; ++nt){
            int j = nt*16 + colj;
            us4 uh, ul;
            #pragma unroll
            for (int rg = 0; rg < 4; ++rg){
                u16 hh,ll; bsplit(acc[tt][nt][rg],hh,ll); uh[rg]=hh; ul[rg]=ll;
            }
            size_t off = ((size_t)j*64 + c)*512 + h0;
            *(us4*)(xwh + off) = uh;
            *(us4*)(xwl + off) = ul;
        }
    }
}

// ================= F2: one mt per block =================
__global__ __launch_bounds__(256) void k_f2(const char* __restrict__ wsb, float* __restrict__ xfP){
    int b = blockIdx.x;             // 120 = kx*6 + mt*2 + kh
    int kx = b/6, r = b%6, mt = r>>1, kh = r&1;
    int lane = threadIdx.x&63, wv = threadIdx.x>>6;
    const u16* thch=(const u16*)(wsb+THC2H); const u16* thcl=(const u16*)(wsb+THC2L);
    const u16* thsh=(const u16*)(wsb+THS2H); const u16* thsl=(const u16*)(wsb+THS2L);
    const u16* xwh=(const u16*)(wsb+XWH);   const u16* xwl=(const u16*)(wsb+XWL);
    f32x4 aA=(f32x4){0,0,0,0}, aB=aA, aC=aA, aD=aA;
    int g8 = (lane>>4)<<3;
    int mrow = lane&15;
    int cB = wv*16 + (lane&15);
    size_t bre = ((size_t)(2*kx)*64 + cB)*512;
    size_t bim = ((size_t)(2*kx+1)*64 + cB)*512;
    for (int kk = kh*8; kk < kh*8+8; ++kk){
        int hof = kk*32 + g8;
        bf16x8 XRh = *reinterpret_cast<const bf16x8*>(xwh + bre + hof);
        bf16x8 XRl = *reinterpret_cast<const bf16x8*>(xwl + bre + hof);
        bf16x8 XIh = *reinterpret_cast<const bf16x8*>(xwh + bim + hof);
        bf16x8 XIl = *reinterpret_cast<const bf16x8*>(xwl + bim + hof);
        size_t ao = (size_t)(mt*16+mrow)*512 + hof;
        bf16x8 Ch = *reinterpret_cast<const bf16x8*>(thch+ao);
        bf16x8 Cl = *reinterpret_cast<const bf16x8*>(thcl+ao);
        bf16x8 Sh = *reinterpret_cast<const bf16x8*>(thsh+ao);
        bf16x8 Sl = *reinterpret_cast<const bf16x8*>(thsl+ao);
        aA=MFMA16(Ch,XRh,aA,0,0,0); aA=MFMA16(Ch,XRl,aA,0,0,0); aA=MFMA16(Cl,XRh,aA,0,0,0);
        aB=MFMA16(Sh,XIh,aB,0,0,0); aB=MFMA16(Sh,XIl,aB,0,0,0); aB=MFMA16(Sl,XIh,aB,0,0,0);
        aC=MFMA16(Ch,XIh,aC,0,0,0); aC=MFMA16(Ch,XIl,aC,0,0,0); aC=MFMA16(Cl,XIh,aC,0,0,0);
        aD=MFMA16(Sh,XRh,aD,0,0,0); aD=MFMA16(Sh,XRl,aD,0,0,0); aD=MFMA16(Sl,XRh,aD,0,0,0);
    }
    #pragma unroll
    for (int rg=0;rg<4;rg++){
        int m = mt*16 + ((lane>>4)<<2) + rg;
        if (m < 40){
            float re = aA[rg]+aB[rg];
            float im = aC[rg]-aD[rg];
            size_t xo = ((size_t)kh*64 + cB)*1600 + (size_t)(m*20+kx)*2;
            xfP[xo] = re; xfP[xo+1] = im;
        }
    }
}

// ================= MIX: 512 blocks (mode-split) =================
__global__ __launch_bounds__(256) void k_mix(const float* __restrict__ w1r,const float* __restrict__ w1i,
    const float* __restrict__ w2r,const float* __restrict__ w2i,
    const float* __restrict__ xfP, float* __restrict__ ypart){
    __shared__ float xs[2][800];
    int b = blockIdx.x;              // 512 = iseg*256 + half*128 + o*2 + mh
    int iseg = b>>8, half = (b>>7)&1, o = (b>>1)&63, mh = b&1;
    int t = threadIdx.x;
    const float* wr = (half? w2r : w1r) + o*400;
    const float* wi = (half? w2i : w1i) + o*400;
    const float* xp0 = xfP + half*800;
    const float* xp1 = xfP + (size_t)64*1600 + half*800;
    int i0 = iseg*32;
    {
        const float* a = xp0 + (size_t)i0*1600; const float* c = xp1 + (size_t)i0*1600;
        xs[0][t]=a[t]+c[t]; xs[0][t+256]=a[t+256]+c[t+256];
        if (t<288) xs[0][t+512]=a[t+512]+c[t+512];
    }
    bool act = t < 200;
    int p1 = mh*200 + (act ? t : 199);
    float ar1=0,ai1=0;
    size_t wof = (size_t)i0*25600;
    float wAr1=wr[wof+p1], wAi1=wi[wof+p1];
    __syncthreads();
    for (int ii=0; ii<32; ++ii){
        int cur = ii&1;
        if (ii<31){
            int i = i0+ii+1;
            const float* a = xp0 + (size_t)i*1600; const float* c = xp1 + (size_t)i*1600;
            float* d = xs[cur^1];
            d[t]=a[t]+c[t]; d[t+256]=a[t+256]+c[t+256];
            if(t<288) d[t+512]=a[t+512]+c[t+512];
        }
        float wBr1=0,wBi1=0;
        if (ii<31){
            size_t wo2 = (size_t)(i0+ii+1)*25600;
            wBr1=wr[wo2+p1]; wBi1=wi[wo2+p1];
        }
        float xr=xs[cur][2*p1], xi=xs[cur][2*p1+1];
        ar1 += xr*wAr1 - xi*wAi1; ai1 += xr*wAi1 + xi*wAr1;
        wAr1=wBr1; wAi1=wBi1;
        __syncthreads();
    }
    if (act){
        int mode1 = half*400 + p1;
        size_t y1 = ((size_t)(iseg*800 + mode1)*64 + o)*2;
        ypart[y1]=ar1; ypart[y1+1]=ai1;
    }
}

// ================= MIXRED =================
__global__ void k_mixred(const float* __restrict__ ypart, char* wsb){
    int g = blockIdx.x*256+threadIdx.x;
    int m = g&63, o=(g>>6)&63, kx=g>>12;
    float vr=0.f, vi=0.f;
    if (m<40){
        int mode = m*20+kx;
        size_t i0 = ((size_t)mode*64+o)*2;
        size_t i1 = ((size_t)(800+mode)*64+o)*2;
        float sc = (kx==0?1.f:2.f)*(1.f/262144.f);
        vr = (ypart[i0]+ypart[i1])*sc;
        vi = (ypart[i0+1]+ypart[i1+1])*sc;
    }
    u16 h,l; size_t yo = ((size_t)kx*64+o)*64+m;
    bsplit(vr,h,l); ((u16*)(wsb+YRH))[yo]=h; ((u16*)(wsb+YRL))[yo]=l;
    bsplit(vi,h,l); ((u16*)(wsb+YIH))[yo]=h; ((u16*)(wsb+YIL))[yo]=l;
}

// ================= I1: 128-thr blocks =================
__global__ __launch_bounds__(128) void k_i1(const char* __restrict__ wsb,
    u16* __restrict__ zh, u16* __restrict__ zl){
    int b = blockIdx.x; int kx = b>>4, hb = b&15;
    int lane = threadIdx.x&63, wv = threadIdx.x>>6;
    const u16* thcAh=(const u16*)(wsb+THCAH); const u16* thcAl=(const u16*)(wsb+THCAL);
    const u16* thsAh=(const u16*)(wsb+THSAH); const u16* thsAl=(const u16*)(wsb+THSAL);
    const u16* thsnh=(const u16*)(wsb+THSNH); const u16* thsnl=(const u16*)(wsb+THSNL);
    const u16* yrh=(const u16*)(wsb+YRH); const u16* yrl=(const u16*)(wsb+YRL);
    const u16* yih=(const u16*)(wsb+YIH); const u16* yil=(const u16*)(wsb+YIL);
    f32x4 aR[4], aI[4];
    #pragma unroll
    for(int nt=0;nt<4;nt++){aR[nt]=(f32x4){0,0,0,0}; aI[nt]=aR[nt];}
    int g8 = (lane>>4)<<3;
    int hrow = hb*32 + wv*16 + (lane&15);
    #pragma unroll
    for (int ks=0; ks<2; ++ks){
        size_t ao = (size_t)hrow*64 + ks*32 + g8;
        bf16x8 Ch=*reinterpret_cast<const bf16x8*>(thcAh+ao);
        bf16x8 Cl=*reinterpret_cast<const bf16x8*>(thcAl+ao);
        bf16x8 Sh=*reinterpret_cast<const bf16x8*>(thsAh+ao);
        bf16x8 Sl=*reinterpret_cast<const bf16x8*>(thsAl+ao);
        bf16x8 Nh=*reinterpret_cast<const bf16x8*>(thsnh+ao);
        bf16x8 Nl=*reinterpret_cast<const bf16x8*>(thsnl+ao);
        #pragma unroll
        for (int nt=0; nt<4; ++nt){
            int o = nt*16+(lane&15);
            size_t bo = ((size_t)kx*64+o)*64 + ks*32 + g8;
            bf16x8 Rh=*reinterpret_cast<const bf16x8*>(yrh+bo);
            bf16x8 Rl=*reinterpret_cast<const bf16x8*>(yrl+bo);
            bf16x8 Ih=*reinterpret_cast<const bf16x8*>(yih+bo);
            bf16x8 Il=*reinterpret_cast<const bf16x8*>(yil+bo);
            aR[nt]=MFMA16(Ch,Rh,aR[nt],0,0,0); aR[nt]=MFMA16(Ch,Rl,aR[nt],0,0,0); aR[nt]=MFMA16(Cl,Rh,aR[nt],0,0,0);
            aR[nt]=MFMA16(Nh,Ih,aR[nt],0,0,0); aR[nt]=MFMA16(Nh,Il,aR[nt],0,0,0); aR[nt]=MFMA16(Nl,Ih,aR[nt],0,0,0);
            aI[nt]=MFMA16(Sh,Rh,aI[nt],0,0,0); aI[nt]=MFMA16(Sh,Rl,aI[nt],0,0,0); aI[nt]=MFMA16(Sl,Rh,aI[nt],0,0,0);
            aI[nt]=MFMA16(Ch,Ih,aI[nt],0,0,0); aI[nt]=MFMA16(Ch,Il,aI[nt],0,0,0); aI[nt]=MFMA16(Cl,Ih,aI[nt],0,0,0);
        }
    }
    #pragma unroll
    for (int nt=0;nt<4;nt++)
        #pragma unroll
        for (int rg=0;rg<4;rg++){
            int h = hb*32 + wv*16 + ((lane>>4)<<2) + rg;
            int o = nt*16+(lane&15);
            size_t za = ((size_t)h*64+o)*64 + 2*kx;
            u16 h1,l1,h2,l2;
            bsplit(aR[nt][rg],h1,l1); bsplit(aI[nt][rg],h2,l2);
            us2 sh={h1,h2}, sl={l1,l2};
            *(us2*)(zh+za)=sh; *(us2*)(zl+za)=sl;
        }
}

// ================= SCT (r6 structure + XCD swizzle) =================
#define SWZ(c,p) ((c) ^ (((p)&7)<<3))
__global__ __launch_bounds__(256) void k_sct(u16* __restrict__ vh, u16* __restrict__ vl,
    const char* __restrict__ wsb, int L, const float* __restrict__ cb,
    const u16* __restrict__ zh, const u16* __restrict__ zl){
    __shared__ u16 sh_[4096];
    __shared__ u16 sl_[4096];
    __shared__ unsigned so_[64*68];
    int bid = ((blockIdx.x & 7) << 9) | (blockIdx.x >> 3);   // 4096 = 8*512 chunked
    int t = threadIdx.x, lane = t&63, wv = t>>6;
    int h = bid>>3, pb = (bid&7)<<6;
    size_t gbase = (size_t)h*512 + pb;
    const u16* cfh=(const u16*)(wsb+CFH); const u16* cfl=(const u16*)(wsb+CFL);
    const u16* t2h=(const u16*)(wsb+T2H); const u16* t2l=(const u16*)(wsb+T2L);
    int g = lane>>4;
    int colp = wv*16 + (lane&15);
    int wt = (pb>>4) + wv;
    // ---- stage loads issue first
    int cst = t>>2, p0s=(t&3)<<4;
    short8 a0 = *(const short8*)(vh + (size_t)cst*NP + gbase + p0s);
    short8 a1 = *(const short8*)(vh + (size_t)cst*NP + gbase + p0s+8);
    short8 b0 = *(const short8*)(vl + (size_t)cst*NP + gbase + p0s);
    short8 b1 = *(const short8*)(vl + (size_t)cst*NP + gbase + p0s+8);
    // ---- ks0 frag loads in flight
    bf16x8 cA0[4][2], zA0[4][2], tB0[2];
    #pragma unroll
    for (int mt=0;mt<4;mt++){
        size_t fo = (size_t)(((L*2+0)*4+mt)*64 + lane)*8;
        cA0[mt][0] = *reinterpret_cast<const bf16x8*>(cfh+fo);
        cA0[mt][1] = *reinterpret_cast<const bf16x8*>(cfl+fo);
        size_t ao = (((size_t)h*64 + mt*16+(lane&15))*64) + (g<<3);
        zA0[mt][0] = *reinterpret_cast<const bf16x8*>(zh+ao);
        zA0[mt][1] = *reinterpret_cast<const bf16x8*>(zl+ao);
    }
    {
        size_t bo = ((size_t)(wt*2+0)*64 + lane)*8;
        tB0[0] = *reinterpret_cast<const bf16x8*>(t2h+bo);
        tB0[1] = *reinterpret_cast<const bf16x8*>(t2l+bo);
    }
    // ---- stage to LDS (swizzled transpose)
    #pragma unroll
    for (int e=0;e<8;e++){
        sh_[(p0s+e)*64 + SWZ(cst,p0s+e)] = (u16)a0[e];
        sh_[(p0s+8+e)*64 + SWZ(cst,p0s+8+e)] = (u16)a1[e];
        sl_[(p0s+e)*64 + SWZ(cst,p0s+e)] = (u16)b0[e];
        sl_[(p0s+8+e)*64 + SWZ(cst,p0s+8+e)] = (u16)b1[e];
    }
    __syncthreads();
    f32x4 acc[4];
    #pragma unroll
    for (int mt=0;mt<4;mt++) acc[mt]=(f32x4){0,0,0,0};
    // ---- ks0 conv
    {
        int so = colp*64 + ((g ^ (colp&7))<<3);
        bf16x8 Bh = *reinterpret_cast<const bf16x8*>(sh_+so);
        bf16x8 Bl = *reinterpret_cast<const bf16x8*>(sl_+so);
        #pragma unroll
        for (int mt=0;mt<4;mt++){
            acc[mt]=MFMA16(cA0[mt][0],Bh,acc[mt],0,0,0);
            acc[mt]=MFMA16(cA0[mt][0],Bl,acc[mt],0,0,0);
            acc[mt]=MFMA16(cA0[mt][1],Bh,acc[mt],0,0,0);
        }
    }
    // ---- issue ks1 loads
    bf16x8 cA1[4][2], zA1[4][2], tB1[2];
    #pragma unroll
    for (int mt=0;mt<4;mt++){
        size_t fo = (size_t)(((L*2+1)*4+mt)*64 + lane)*8;
        cA1[mt][0] = *reinterpret_cast<const bf16x8*>(cfh+fo);
        cA1[mt][1] = *reinterpret_cast<const bf16x8*>(cfl+fo);
        size_t ao = (((size_t)h*64 + mt*16+(lane&15))*64) + 32 + (g<<3);
        zA1[mt][0] = *reinterpret_cast<const bf16x8*>(zh+ao);
        zA1[mt][1] = *reinterpret_cast<const bf16x8*>(zl+ao);
    }
    {
        size_t bo = ((size_t)(wt*2+1)*64 + lane)*8;
        tB1[0] = *reinterpret_cast<const bf16x8*>(t2h+bo);
        tB1[1] = *reinterpret_cast<const bf16x8*>(t2l+bo);
    }
    // ---- ks0 spectral
    #pragma unroll
    for (int mt=0;mt<4;mt++){
        acc[mt]=MFMA16(zA0[mt][0],tB0[0],acc[mt],0,0,0);
        acc[mt]=MFMA16(zA0[mt][0],tB0[1],acc[mt],0,0,0);
        acc[mt]=MFMA16(zA0[mt][1],tB0[0],acc[mt],0,0,0);
    }
    // ---- ks1 conv
    {
        int so = colp*64 + (((4+g) ^ (colp&7))<<3);
        bf16x8 Bh = *reinterpret_cast<const bf16x8*>(sh_+so);
        bf16x8 Bl = *reinterpret_cast<const bf16x8*>(sl_+so);
        #pragma unroll
        for (int mt=0;mt<4;mt++){
            acc[mt]=MFMA16(cA1[mt][0],Bh,acc[mt],0,0,0);
            acc[mt]=MFMA16(cA1[mt][0],Bl,acc[mt],0,0,0);
            acc[mt]=MFMA16(cA1[mt][1],Bh,acc[mt],0,0,0);
        }
    }
    // ---- ks1 spectral
    #pragma unroll
    for (int mt=0;mt<4;mt++){
        acc[mt]=MFMA16(zA1[mt][0],tB1[0],acc[mt],0,0,0);
        acc[mt]=MFMA16(zA1[mt][0],tB1[1],acc[mt],0,0,0);
        acc[mt]=MFMA16(zA1[mt][1],tB1[0],acc[mt],0,0,0);
    }
    // ---- epilogue: tanh+split into padded LDS, then coalesced stores
    #pragma unroll
    for (int mt=0;mt<4;mt++){
        float4 cbv = *reinterpret_cast<const float4*>(cb + mt*16 + (g<<2));
        float cba[4] = {cbv.x, cbv.y, cbv.z, cbv.w};
        #pragma unroll
        for (int rg=0;rg<4;rg++){
            int o = mt*16 + (g<<2) + rg;
            float val = tanhfast(acc[mt][rg] + cba[rg]);
            u16 hh,ll; bsplit(val,hh,ll);
            so_[o*68 + colp] = (unsigned)hh | ((unsigned)ll<<16);
        }
    }
    __syncthreads();
    {
        int o = t>>2, p0 = (t&3)<<4;
        const uint4* sp = reinterpret_cast<const uint4*>(so_ + o*68 + p0);
        uint4 u0 = sp[0], u1 = sp[1], u2 = sp[2], u3 = sp[3];
        us8 h0, h1, l0, l1;
        h0[0]=(u16)u0.x; l0[0]=(u16)(u0.x>>16);
        h0[1]=(u16)u0.y; l0[1]=(u16)(u0.y>>16);
        h0[2]=(u16)u0.z; l0[2]=(u16)(u0.z>>16);
        h0[3]=(u16)u0.w; l0[3]=(u16)(u0.w>>16);
        h0[4]=(u16)u1.x; l0[4]=(u16)(u1.x>>16);
        h0[5]=(u16)u1.y; l0[5]=(u16)(u1.y>>16);
        h0[6]=(u16)u1.z; l0[6]=(u16)(u1.z>>16);
        h0[7]=(u16)u1.w; l0[7]=(u16)(u1.w>>16);
        h1[0]=(u16)u2.x; l1[0]=(u16)(u2.x>>16);
        h1[1]=(u16)u2.y; l1[1]=(u16)(u2.y>>16);
        h1[2]=(u16)u2.z; l1[2]=(u16)(u2.z>>16);
        h1[3]=(u16)u2.w; l1[3]=(u16)(u2.w>>16);
        h1[4]=(u16)u3.x; l1[4]=(u16)(u3.x>>16);
        h1[5]=(u16)u3.y; l1[5]=(u16)(u3.y>>16);
        h1[6]=(u16)u3.z; l1[6]=(u16)(u3.z>>16);
        h1[7]=(u16)u3.w; l1[7]=(u16)(u3.w>>16);
        size_t go = (size_t)o*NP + gbase + p0;
        *(us8*)(vh+go)   = h0;
        *(us8*)(vh+go+8) = h1;
        *(us8*)(vl+go)   = l0;
        *(us8*)(vl+go+8) = l1;
    }
}

// ================= FC1+FC2 (XCD swizzle) =================
__global__ __launch_bounds__(256) void k_fc12(const u16* __restrict__ vh, const u16* __restrict__ vl,
    const char* __restrict__ wsb, const float* __restrict__ b1,
    const float* __restrict__ w2, const float* __restrict__ b2, float* __restrict__ out){
    __shared__ u16 sh_[4096];
    __shared__ u16 sl_[4096];
    int bid = ((blockIdx.x & 7) << 9) | (blockIdx.x >> 3);   // 4096 = 8*512 chunked
    int t = threadIdx.x, lane = t&63, wv = t>>6;
    size_t pb = (size_t)bid*64;
    {
        int c = t>>2, p0=(t&3)<<4;
        short8 a0 = *(const short8*)(vh + (size_t)c*NP + pb + p0);
        short8 a1 = *(const short8*)(vh + (size_t)c*NP + pb + p0+8);
        short8 b0 = *(const short8*)(vl + (size_t)c*NP + pb + p0);
        short8 b1 = *(const short8*)(vl + (size_t)c*NP + pb + p0+8);
        #pragma unroll
        for (int e=0;e<8;e++){
            sh_[(p0+e)*64 + SWZ(c,p0+e)] = (u16)a0[e];
            sh_[(p0+8+e)*64 + SWZ(c,p0+8+e)] = (u16)a1[e];
            sl_[(p0+e)*64 + SWZ(c,p0+e)] = (u16)b0[e];
            sl_[(p0+8+e)*64 + SWZ(c,p0+8+e)] = (u16)b1[e];
        }
    }
    __syncthreads();
    f32x4 acc[8];
    #pragma unroll
    for (int mt=0;mt<8;mt++) acc[mt]=(f32x4){0,0,0,0};
    int colp = wv*16 + (lane&15);
    int g = lane>>4;
    const u16* f1h=(const u16*)(wsb+F1H); const u16* f1l=(const u16*)(wsb+F1L);
    #pragma unroll
    for (int ks=0;ks<2;ks++){
        bf16x8 A[8][2];
        #pragma unroll
        for (int mt=0;mt<8;mt++){
            size_t fo = (size_t)((ks*8+mt)*64 + lane)*8;
            A[mt][0] = *reinterpret_cast<const bf16x8*>(f1h+fo);
            A[mt][1] = *reinterpret_cast<const bf16x8*>(f1l+fo);
        }
        int o8 = ks*4+g;
        int so = colp*64 + ((o8 ^ (colp&7))<<3);
        bf16x8 Bh = *reinterpret_cast<const bf16x8*>(sh_+so);
        bf16x8 Bl = *reinterpret_cast<const bf16x8*>(sl_+so);
        #pragma unroll
        for (int mt=0;mt<8;mt++){
            acc[mt]=MFMA16(A[mt][0],Bh,acc[mt],0,0,0);
            acc[mt]=MFMA16(A[mt][0],Bl,acc[mt],0,0,0);
            acc[mt]=MFMA16(A[mt][1],Bh,acc[mt],0,0,0);
        }
    }
    float s = 0.f;
    #pragma unroll
    for (int mt=0;mt<8;mt++)
        #pragma unroll
        for (int rg=0;rg<4;rg++){
            int f = mt*16 + (g<<2) + rg;
            s += w2[f] * tanhfast(acc[mt][rg] + b1[f]);
        }
    s += __shfl_xor(s, 16);
    s += __shfl_xor(s, 32);
    if (lane < 16) out[pb + wv*16 + lane] = s + b2[0];
}

extern "C" void kernel_launch(void* const* d_in, const int* in_sizes, int n_in,
                              void* d_out, int out_size, void* d_ws, size_t ws_size,
                              hipStream_t stream) {
    const float* x     = (const float*)d_in[0];
    const float* fc0w  = (const float*)d_in[1];
    const float* fc0b  = (const float*)d_in[2];
    const float* sw1r  = (const float*)d_in[3];
    const float* sw1i  = (const float*)d_in[4];
    const float* sw2r  = (const float*)d_in[5];
    const float* sw2i  = (const float*)d_in[6];
    const float* convw = (const float*)d_in[7];
    const float* convb = (const float*)d_in[8];
    const float* fc1w  = (const float*)d_in[9];
    const float* fc1b  = (const float*)d_in[10];
    const float* fc2w  = (const float*)d_in[11];
    const float* fc2b  = (const float*)d_in[12];
    char* wsb = (char*)d_ws;
    float* out = (float*)d_out;

    u16* twh = (u16*)(wsb+TWH); u16* twl = (u16*)(wsb+TWL);
    u16* xwh = (u16*)(wsb+XWH); u16* xwl = (u16*)(wsb+XWL);
    float* xfP = (float*)(wsb+XFP);
    float* ypart = (float*)(wsb+YPART);
    u16* zh = (u16*)(wsb+ZH); u16* zl = (u16*)(wsb+ZL);
    u16* vh = (u16*)(wsb+VH); u16* vl = (u16*)(wsb+VL);

    k_setup<<<544, 256, 0, stream>>>(wsb, convw, fc1w);
    k_fc0<<<256, 256, 0, stream>>>(x, fc0w, fc0b, vh, vl);
    for (int L = 0; L < 4; ++L){
        size_t so = (size_t)L * 64 * 64 * 400;
        k_f1<<<256, 256, 0, stream>>>(vh, vl, twh, twl, xwh, xwl);
        k_f2<<<120, 256, 0, stream>>>(wsb, xfP);
        k_mix<<<512, 256, 0, stream>>>(sw1r+so, sw1i+so, sw2r+so, sw2i+so, xfP, ypart);
        k_mixred<<<320, 256, 0, stream>>>(ypart, wsb);
        k_i1<<<320, 128, 0, stream>>>(wsb, zh, zl);
        k_sct<<<4096, 256, 0, stream>>>(vh, vl, wsb, L, convb + (size_t)L*64, zh, zl);
    }
    k_fc12<<<4096, 256, 0, stream>>>(vh, vl, wsb, fc1b, fc2w, fc2b, out);
}

// Round 10
// 729.306 us; speedup vs baseline: 1.0230x; 1.0230x over previous
//
#include <hip/hip_runtime.h>
#include <math.h>

typedef unsigned short u16;
typedef __attribute__((ext_vector_type(8))) short short8;
typedef __attribute__((ext_vector_type(8))) short bf16x8;
typedef __attribute__((ext_vector_type(4))) unsigned short us4;
typedef __attribute__((ext_vector_type(2))) unsigned short us2;
typedef __attribute__((ext_vector_type(8))) unsigned short us8;
typedef __attribute__((ext_vector_type(4))) float f32x4;

#define NP (512*512)
#define MFMA16 __builtin_amdgcn_mfma_f32_16x16x32_bf16

// ---- workspace byte offsets (all 256-aligned) ----
#define TWH   0u
#define TWL   49152u
#define T2H   98304u
#define T2L   163840u
#define THC2H 229376u
#define THC2L 278528u
#define THS2H 327680u
#define THS2L 376832u
#define THCAH 425984u
#define THCAL 491520u
#define THSAH 557056u
#define THSAL 622592u
#define THSNH 688128u
#define THSNL 753664u
#define CFH   819200u
#define CFL   851968u
#define F1H   884736u
#define F1L   901120u
#define XWH   917504u
#define XWL   4063232u
#define XFP   7208960u
#define YPART 8028160u
#define YRH   8847360u
#define YRL   9011200u
#define YIH   9175040u
#define YIL   9338880u
#define ZH    9502720u
#define ZL    13697024u
#define VH    17891328u
#define VL    51445760u

// HW bf16 round-to-nearest-even via v_cvt_pk_bf16_f32.
// cvt_pk(x,x) puts bf16(x) in BOTH halves -> taking low 16 is order-safe.
__device__ __forceinline__ u16 bf16rne(float x){
    unsigned r;
    asm("v_cvt_pk_bf16_f32 %0, %1, %1" : "=v"(r) : "v"(x));
    return (u16)r;
}
__device__ __forceinline__ float fbf(u16 h){ return __uint_as_float(((unsigned)h)<<16); }
__device__ __forceinline__ void bsplit(float x, u16& h, u16& l){
    h = bf16rne(x); l = bf16rne(x - fbf(h));
}
__device__ __forceinline__ float tanhfast(float x){
    x = fminf(10.f, fmaxf(-10.f, x));
    float e = __expf(2.f*x);
    return (e-1.f)/(e+1.f);
}

// ================= setup: tables + weight frags =================
__global__ void k_setup(char* wsb, const float* __restrict__ convw, const float* __restrict__ fc1w){
    int i = blockIdx.x*256 + threadIdx.x;
    const float c2pi = 6.283185307179586f/512.0f;
    if (i < 24576){                         // TW
        int e=i&7, lane=(i>>3)&63, g=i>>9; int nt=g%3;
        int k = (g/3)*32 + ((lane>>4)<<3) + e;
        int n = nt*16 + (lane&15);
        float v=0.f;
        if(n<40){int kx=n>>1; float a=c2pi*(float)((kx*k)&511); v=(n&1)?-sinf(a):cosf(a);}
        u16 h,l; bsplit(v,h,l);
        ((u16*)(wsb+TWH))[i]=h; ((u16*)(wsb+TWL))[i]=l;
    } else if (i < 57344){                  // T2
        int j2=i-24576;
        int e=j2&7, lane=(j2>>3)&63, g=j2>>9; int ks=g&1, wt=g>>1;
        int j = ks*32 + ((lane>>4)<<3) + e;
        int w = wt*16 + (lane&15);
        float v=0.f;
        if(j<40){int kx=j>>1; float a=c2pi*(float)((kx*w)&511); v=(j&1)?-sinf(a):cosf(a);}
        u16 h,l; bsplit(v,h,l);
        ((u16*)(wsb+T2H))[j2]=h; ((u16*)(wsb+T2L))[j2]=l;
    } else if (i < 81920){                  // f2 A [m48][h512]
        int j2 = i-57344;
        int m=j2>>9, hh=j2&511;
        float vc=0.f,vs=0.f;
        if(m<40){int ky=(m<20)?m:(472+m); float a=c2pi*(float)((ky*hh)&511); vc=cosf(a); vs=sinf(a);}
        u16 h,l;
        bsplit(vc,h,l); ((u16*)(wsb+THC2H))[j2]=h; ((u16*)(wsb+THC2L))[j2]=l;
        bsplit(vs,h,l); ((u16*)(wsb+THS2H))[j2]=h; ((u16*)(wsb+THS2L))[j2]=l;
    } else if (i < 114688){                 // i1 A [h512][m64]
        int j2 = i-81920;
        int hh=j2>>6, m=j2&63;
        float vc=0.f,vs=0.f;
        if(m<40){int ky=(m<20)?m:(472+m); float a=c2pi*(float)((ky*hh)&511); vc=cosf(a); vs=sinf(a);}
        u16 h,l;
        bsplit(vc,h,l);  ((u16*)(wsb+THCAH))[j2]=h; ((u16*)(wsb+THCAL))[j2]=l;
        bsplit(vs,h,l);  ((u16*)(wsb+THSAH))[j2]=h; ((u16*)(wsb+THSAL))[j2]=l;
        bsplit(-vs,h,l); ((u16*)(wsb+THSNH))[j2]=h; ((u16*)(wsb+THSNL))[j2]=l;
    } else {                                // weight frags
        int j = i - 114688;
        if (j < 16384){
            int e=j&7, lane=(j>>3)&63, g=j>>9;
            int mt=g&3, ks=(g>>2)&1, L=g>>3;
            int o = mt*16+(lane&15), c = ks*32+((lane>>4)<<3)+e;
            float v = convw[L*4096 + o*64 + c];
            u16 h,l; bsplit(v,h,l);
            ((u16*)(wsb+CFH))[j]=h; ((u16*)(wsb+CFL))[j]=l;
        } else {
            int j2=j-16384;
            int e=j2&7, lane=(j2>>3)&63, g=j2>>9;
            int mt=g&7, ks=g>>3;
            int f = mt*16+(lane&15), c = ks*32+((lane>>4)<<3)+e;
            float v = fc1w[f*64+c];
            u16 h,l; bsplit(v,h,l);
            ((u16*)(wsb+F1H))[j2]=h; ((u16*)(wsb+F1L))[j2]=l;
        }
    }
}

// ================= fc0 =================
__global__ __launch_bounds__(256) void k_fc0(const float* __restrict__ x,
    const float* __restrict__ w, const float* __restrict__ b,
    u16* __restrict__ vh, u16* __restrict__ vl){
    __shared__ float xs[1024*3];
    __shared__ float ws3[192], bs[64];
    int t = threadIdx.x;
    size_t pb = (size_t)blockIdx.x*1024;
    const float4* xg = (const float4*)(x + pb*3);
    float4* xs4 = (float4*)xs;
    #pragma unroll
    for (int k=0;k<3;k++) xs4[t + k*256] = xg[t + k*256];
    if (t<192) ws3[t]=w[t];
    if (t<64) bs[t]=b[t];
    __syncthreads();
    int p0 = t*4;
    float X0[4],X1[4],X2[4];
    #pragma unroll
    for(int e=0;e<4;e++){X0[e]=xs[(p0+e)*3];X1[e]=xs[(p0+e)*3+1];X2[e]=xs[(p0+e)*3+2];}
    for (int c=0;c<64;c++){
        float w0=ws3[c*3],w1=ws3[c*3+1],w2=ws3[c*3+2],bc=bs[c];
        us4 sh, sl;
        #pragma unroll
        for(int e=0;e<4;e++){
            float v = w0*X0[e]+w1*X1[e]+w2*X2[e]+bc;
            u16 hh,ll; bsplit(v,hh,ll); sh[e]=hh; sl[e]=ll;
        }
        *(us4*)(vh + (size_t)c*NP + pb + p0) = sh;
        *(us4*)(vl + (size_t)c*NP + pb + p0) = sl;
    }
}

// ================= F1: 2 row-tiles per wave, shared B, XCD swizzle =================
__global__ __launch_bounds__(256) void k_f1(const u16* __restrict__ vh, const u16* __restrict__ vl,
    const u16* __restrict__ twh, const u16* __restrict__ twl,
    u16* __restrict__ xwh, u16* __restrict__ xwl){
    int bid = ((blockIdx.x & 7) << 5) | (blockIdx.x >> 3);   // 256 = 8*32 chunked
    int lane = threadIdx.x & 63, wv = threadIdx.x >> 6;
    int r0a = bid*128 + wv*16;
    int r1a = r0a + 64;
    int rl = lane&15;
    const u16* ah0 = vh + (size_t)(r0a+rl)*512 + ((lane>>4)<<3);
    const u16* al0 = vl + (size_t)(r0a+rl)*512 + ((lane>>4)<<3);
    const u16* ah1 = vh + (size_t)(r1a+rl)*512 + ((lane>>4)<<3);
    const u16* al1 = vl + (size_t)(r1a+rl)*512 + ((lane>>4)<<3);
    f32x4 acc[2][3];
    #pragma unroll
    for (int tt = 0; tt < 2; ++tt)
        #pragma unroll
        for (int nt = 0; nt < 3; ++nt) acc[tt][nt] = (f32x4){0.f,0.f,0.f,0.f};
    #pragma unroll 2
    for (int kk = 0; kk < 16; ++kk){
        bf16x8 Bh[3], Bl[3];
        #pragma unroll
        for (int nt = 0; nt < 3; ++nt){
            size_t bo = ((size_t)(kk*3+nt)*64 + lane)*8;
            Bh[nt] = *reinterpret_cast<const bf16x8*>(twh + bo);
            Bl[nt] = *reinterpret_cast<const bf16x8*>(twl + bo);
        }
        bf16x8 Ah0 = *reinterpret_cast<const bf16x8*>(ah0 + kk*32);
        bf16x8 Al0 = *reinterpret_cast<const bf16x8*>(al0 + kk*32);
        bf16x8 Ah1 = *reinterpret_cast<const bf16x8*>(ah1 + kk*32);
        bf16x8 Al1 = *reinterpret_cast<const bf16x8*>(al1 + kk*32);
        #pragma unroll
        for (int nt = 0; nt < 3; ++nt){
            acc[0][nt] = MFMA16(Ah0, Bh[nt], acc[0][nt], 0,0,0);
            acc[0][nt] = MFMA16(Ah0, Bl[nt], acc[0][nt], 0,0,0);
            acc[0][nt] = MFMA16(Al0, Bh[nt], acc[0][nt], 0,0,0);
            acc[1][nt] = MFMA16(Ah1, Bh[nt], acc[1][nt], 0,0,0);
            acc[1][nt] = MFMA16(Ah1, Bl[nt], acc[1][nt], 0,0,0);
            acc[1][nt] = MFMA16(Al1, Bh[nt], acc[1][nt], 0,0,0);
        }
    }
    int colj = lane&15;
    #pragma unroll
    for (int tt = 0; tt < 2; ++tt){
        int r0 = (tt ? r1a : r0a) + ((lane>>4)<<2);
        int c = r0>>9, h0 = r0&511;
        #pragma unroll
        for (int nt = 0; nt < 3; ++nt){
            int j = nt*16 + colj;
            us4 uh, ul;
            #pragma unroll
            for (int rg = 0; rg < 4; ++rg){
                u16 hh,ll; bsplit(acc[tt][nt][rg],hh,ll); uh[rg]=hh; ul[rg]=ll;
            }
            size_t off = ((size_t)j*64 + c)*512 + h0;
            *(us4*)(xwh + off) = uh;
            *(us4*)(xwl + off) = ul;
        }
    }
}

// ================= F2: one mt per block =================
__global__ __launch_bounds__(256) void k_f2(const char* __restrict__ wsb, float* __restrict__ xfP){
    int b = blockIdx.x;             // 120 = kx*6 + mt*2 + kh
    int kx = b/6, r = b%6, mt = r>>1, kh = r&1;
    int lane = threadIdx.x&63, wv = threadIdx.x>>6;
    const u16* thch=(const u16*)(wsb+THC2H); const u16* thcl=(const u16*)(wsb+THC2L);
    const u16* thsh=(const u16*)(wsb+THS2H); const u16* thsl=(const u16*)(wsb+THS2L);
    const u16* xwh=(const u16*)(wsb+XWH);   const u16* xwl=(const u16*)(wsb+XWL);
    f32x4 aA=(f32x4){0,0,0,0}, aB=aA, aC=aA, aD=aA;
    int g8 = (lane>>4)<<3;
    int mrow = lane&15;
    int cB = wv*16 + (lane&15);
    size_t bre = ((size_t)(2*kx)*64 + cB)*512;
    size_t bim = ((size_t)(2*kx+1)*64 + cB)*512;
    for (int kk = kh*8; kk < kh*8+8; ++kk){
        int hof = kk*32 + g8;
        bf16x8 XRh = *reinterpret_cast<const bf16x8*>(xwh + bre + hof);
        bf16x8 XRl = *reinterpret_cast<const bf16x8*>(xwl + bre + hof);
        bf16x8 XIh = *reinterpret_cast<const bf16x8*>(xwh + bim + hof);
        bf16x8 XIl = *reinterpret_cast<const bf16x8*>(xwl + bim + hof);
        size_t ao = (size_t)(mt*16+mrow)*512 + hof;
        bf16x8 Ch = *reinterpret_cast<const bf16x8*>(thch+ao);
        bf16x8 Cl = *reinterpret_cast<const bf16x8*>(thcl+ao);
        bf16x8 Sh = *reinterpret_cast<const bf16x8*>(thsh+ao);
        bf16x8 Sl = *reinterpret_cast<const bf16x8*>(thsl+ao);
        aA=MFMA16(Ch,XRh,aA,0,0,0); aA=MFMA16(Ch,XRl,aA,0,0,0); aA=MFMA16(Cl,XRh,aA,0,0,0);
        aB=MFMA16(Sh,XIh,aB,0,0,0); aB=MFMA16(Sh,XIl,aB,0,0,0); aB=MFMA16(Sl,XIh,aB,0,0,0);
        aC=MFMA16(Ch,XIh,aC,0,0,0); aC=MFMA16(Ch,XIl,aC,0,0,0); aC=MFMA16(Cl,XIh,aC,0,0,0);
        aD=MFMA16(Sh,XRh,aD,0,0,0); aD=MFMA16(Sh,XRl,aD,0,0,0); aD=MFMA16(Sl,XRh,aD,0,0,0);
    }
    #pragma unroll
    for (int rg=0;rg<4;rg++){
        int m = mt*16 + ((lane>>4)<<2) + rg;
        if (m < 40){
            float re = aA[rg]+aB[rg];
            float im = aC[rg]-aD[rg];
            size_t xo = ((size_t)kh*64 + cB)*1600 + (size_t)(m*20+kx)*2;
            xfP[xo] = re; xfP[xo+1] = im;
        }
    }
}

// ================= MIX (r6 version: 256 blocks, dual accumulator) =================
__global__ __launch_bounds__(256) void k_mix(const float* __restrict__ w1r,const float* __restrict__ w1i,
    const float* __restrict__ w2r,const float* __restrict__ w2i,
    const float* __restrict__ xfP, float* __restrict__ ypart){
    __shared__ float xs[2][800];
    int b = blockIdx.x;
    int iseg = b>>7, half = (b>>6)&1, o = b&63;
    int t = threadIdx.x;
    const float* wr = (half? w2r : w1r) + o*400;
    const float* wi = (half? w2i : w1i) + o*400;
    const float* xp0 = xfP + half*800;
    const float* xp1 = xfP + (size_t)64*1600 + half*800;
    int i0 = iseg*32;
    {
        const float* a = xp0 + (size_t)i0*1600; const float* c = xp1 + (size_t)i0*1600;
        xs[0][t]=a[t]+c[t]; xs[0][t+256]=a[t+256]+c[t+256];
        if (t<288) xs[0][t+512]=a[t+512]+c[t+512];
    }
    int p1 = t, p2 = t+256; bool has2 = (p2<400);
    float ar1=0,ai1=0,ar2=0,ai2=0;
    size_t wof = (size_t)i0*25600;
    float wAr1=wr[wof+p1], wAi1=wi[wof+p1];
    float wAr2=0,wAi2=0;
    if(has2){ wAr2=wr[wof+p2]; wAi2=wi[wof+p2]; }
    __syncthreads();
    for (int ii=0; ii<32; ++ii){
        int cur = ii&1;
        if (ii<31){
            int i = i0+ii+1;
            const float* a = xp0 + (size_t)i*1600; const float* c = xp1 + (size_t)i*1600;
            float* d = xs[cur^1];
            d[t]=a[t]+c[t]; d[t+256]=a[t+256]+c[t+256];
            if(t<288) d[t+512]=a[t+512]+c[t+512];
        }
        float wBr1=0,wBi1=0,wBr2=0,wBi2=0;
        if (ii<31){
            size_t wo2 = (size_t)(i0+ii+1)*25600;
            wBr1=wr[wo2+p1]; wBi1=wi[wo2+p1];
            if(has2){ wBr2=wr[wo2+p2]; wBi2=wi[wo2+p2]; }
        }
        float xr=xs[cur][2*p1], xi=xs[cur][2*p1+1];
        ar1 += xr*wAr1 - xi*wAi1; ai1 += xr*wAi1 + xi*wAr1;
        if (has2){
            float xr2=xs[cur][2*p2], xi2=xs[cur][2*p2+1];
            ar2 += xr2*wAr2 - xi2*wAi2; ai2 += xr2*wAi2 + xi2*wAr2;
        }
        wAr1=wBr1; wAi1=wBi1; wAr2=wBr2; wAi2=wBi2;
        __syncthreads();
    }
    int mode1 = half*400 + p1;
    size_t y1 = ((size_t)(iseg*800 + mode1)*64 + o)*2;
    ypart[y1]=ar1; ypart[y1+1]=ai1;
    if (has2){
        int mode2 = half*400 + p2;
        size_t y2 = ((size_t)(iseg*800 + mode2)*64 + o)*2;
        ypart[y2]=ar2; ypart[y2+1]=ai2;
    }
}

// ================= MIXRED =================
__global__ void k_mixred(const float* __restrict__ ypart, char* wsb){
    int g = blockIdx.x*256+threadIdx.x;
    int m = g&63, o=(g>>6)&63, kx=g>>12;
    float vr=0.f, vi=0.f;
    if (m<40){
        int mode = m*20+kx;
        size_t i0 = ((size_t)mode*64+o)*2;
        size_t i1 = ((size_t)(800+mode)*64+o)*2;
        float sc = (kx==0?1.f:2.f)*(1.f/262144.f);
        vr = (ypart[i0]+ypart[i1])*sc;
        vi = (ypart[i0+1]+ypart[i1+1])*sc;
    }
    u16 h,l; size_t yo = ((size_t)kx*64+o)*64+m;
    bsplit(vr,h,l); ((u16*)(wsb+YRH))[yo]=h; ((u16*)(wsb+YRL))[yo]=l;
    bsplit(vi,h,l); ((u16*)(wsb+YIH))[yo]=h; ((u16*)(wsb+YIL))[yo]=l;
}

// ================= I1: 128-thr blocks =================
__global__ __launch_bounds__(128) void k_i1(const char* __restrict__ wsb,
    u16* __restrict__ zh, u16* __restrict__ zl){
    int b = blockIdx.x; int kx = b>>4, hb = b&15;
    int lane = threadIdx.x&63, wv = threadIdx.x>>6;
    const u16* thcAh=(const u16*)(wsb+THCAH); const u16* thcAl=(const u16*)(wsb+THCAL);
    const u16* thsAh=(const u16*)(wsb+THSAH); const u16* thsAl=(const u16*)(wsb+THSAL);
    const u16* thsnh=(const u16*)(wsb+THSNH); const u16* thsnl=(const u16*)(wsb+THSNL);
    const u16* yrh=(const u16*)(wsb+YRH); const u16* yrl=(const u16*)(wsb+YRL);
    const u16* yih=(const u16*)(wsb+YIH); const u16* yil=(const u16*)(wsb+YIL);
    f32x4 aR[4], aI[4];
    #pragma unroll
    for(int nt=0;nt<4;nt++){aR[nt]=(f32x4){0,0,0,0}; aI[nt]=aR[nt];}
    int g8 = (lane>>4)<<3;
    int hrow = hb*32 + wv*16 + (lane&15);
    #pragma unroll
    for (int ks=0; ks<2; ++ks){
        size_t ao = (size_t)hrow*64 + ks*32 + g8;
        bf16x8 Ch=*reinterpret_cast<const bf16x8*>(thcAh+ao);
        bf16x8 Cl=*reinterpret_cast<const bf16x8*>(thcAl+ao);
        bf16x8 Sh=*reinterpret_cast<const bf16x8*>(thsAh+ao);
        bf16x8 Sl=*reinterpret_cast<const bf16x8*>(thsAl+ao);
        bf16x8 Nh=*reinterpret_cast<const bf16x8*>(thsnh+ao);
        bf16x8 Nl=*reinterpret_cast<const bf16x8*>(thsnl+ao);
        #pragma unroll
        for (int nt=0; nt<4; ++nt){
            int o = nt*16+(lane&15);
            size_t bo = ((size_t)kx*64+o)*64 + ks*32 + g8;
            bf16x8 Rh=*reinterpret_cast<const bf16x8*>(yrh+bo);
            bf16x8 Rl=*reinterpret_cast<const bf16x8*>(yrl+bo);
            bf16x8 Ih=*reinterpret_cast<const bf16x8*>(yih+bo);
            bf16x8 Il=*reinterpret_cast<const bf16x8*>(yil+bo);
            aR[nt]=MFMA16(Ch,Rh,aR[nt],0,0,0); aR[nt]=MFMA16(Ch,Rl,aR[nt],0,0,0); aR[nt]=MFMA16(Cl,Rh,aR[nt],0,0,0);
            aR[nt]=MFMA16(Nh,Ih,aR[nt],0,0,0); aR[nt]=MFMA16(Nh,Il,aR[nt],0,0,0); aR[nt]=MFMA16(Nl,Ih,aR[nt],0,0,0);
            aI[nt]=MFMA16(Sh,Rh,aI[nt],0,0,0); aI[nt]=MFMA16(Sh,Rl,aI[nt],0,0,0); aI[nt]=MFMA16(Sl,Rh,aI[nt],0,0,0);
            aI[nt]=MFMA16(Ch,Ih,aI[nt],0,0,0); aI[nt]=MFMA16(Ch,Il,aI[nt],0,0,0); aI[nt]=MFMA16(Cl,Ih,aI[nt],0,0,0);
        }
    }
    #pragma unroll
    for (int nt=0;nt<4;nt++)
        #pragma unroll
        for (int rg=0;rg<4;rg++){
            int h = hb*32 + wv*16 + ((lane>>4)<<2) + rg;
            int o = nt*16+(lane&15);
            size_t za = ((size_t)h*64+o)*64 + 2*kx;
            u16 h1,l1,h2,l2;
            bsplit(aR[nt][rg],h1,l1); bsplit(aI[nt][rg],h2,l2);
            us2 sh={h1,h2}, sl={l1,l2};
            *(us2*)(zh+za)=sh; *(us2*)(zl+za)=sl;
        }
}

// ================= SCT (r6 structure + XCD swizzle) =================
#define SWZ(c,p) ((c) ^ (((p)&7)<<3))
__global__ __launch_bounds__(256) void k_sct(u16* __restrict__ vh, u16* __restrict__ vl,
    const char* __restrict__ wsb, int L, const float* __restrict__ cb,
    const u16* __restrict__ zh, const u16* __restrict__ zl){
    __shared__ u16 sh_[4096];
    __shared__ u16 sl_[4096];
    __shared__ unsigned so_[64*68];
    int bid = ((blockIdx.x & 7) << 9) | (blockIdx.x >> 3);   // 4096 = 8*512 chunked
    int t = threadIdx.x, lane = t&63, wv = t>>6;
    int h = bid>>3, pb = (bid&7)<<6;
    size_t gbase = (size_t)h*512 + pb;
    const u16* cfh=(const u16*)(wsb+CFH); const u16* cfl=(const u16*)(wsb+CFL);
    const u16* t2h=(const u16*)(wsb+T2H); const u16* t2l=(const u16*)(wsb+T2L);
    int g = lane>>4;
    int colp = wv*16 + (lane&15);
    int wt = (pb>>4) + wv;
    // ---- stage loads issue first
    int cst = t>>2, p0s=(t&3)<<4;
    short8 a0 = *(const short8*)(vh + (size_t)cst*NP + gbase + p0s);
    short8 a1 = *(const short8*)(vh + (size_t)cst*NP + gbase + p0s+8);
    short8 b0 = *(const short8*)(vl + (size_t)cst*NP + gbase + p0s);
    short8 b1 = *(const short8*)(vl + (size_t)cst*NP + gbase + p0s+8);
    // ---- ks0 frag loads in flight
    bf16x8 cA0[4][2], zA0[4][2], tB0[2];
    #pragma unroll
    for (int mt=0;mt<4;mt++){
        size_t fo = (size_t)(((L*2+0)*4+mt)*64 + lane)*8;
        cA0[mt][0] = *reinterpret_cast<const bf16x8*>(cfh+fo);
        cA0[mt][1] = *reinterpret_cast<const bf16x8*>(cfl+fo);
        size_t ao = (((size_t)h*64 + mt*16+(lane&15))*64) + (g<<3);
        zA0[mt][0] = *reinterpret_cast<const bf16x8*>(zh+ao);
        zA0[mt][1] = *reinterpret_cast<const bf16x8*>(zl+ao);
    }
    {
        size_t bo = ((size_t)(wt*2+0)*64 + lane)*8;
        tB0[0] = *reinterpret_cast<const bf16x8*>(t2h+bo);
        tB0[1] = *reinterpret_cast<const bf16x8*>(t2l+bo);
    }
    // ---- stage to LDS (swizzled transpose)
    #pragma unroll
    for (int e=0;e<8;e++){
        sh_[(p0s+e)*64 + SWZ(cst,p0s+e)] = (u16)a0[e];
        sh_[(p0s+8+e)*64 + SWZ(cst,p0s+8+e)] = (u16)a1[e];
        sl_[(p0s+e)*64 + SWZ(cst,p0s+e)] = (u16)b0[e];
        sl_[(p0s+8+e)*64 + SWZ(cst,p0s+8+e)] = (u16)b1[e];
    }
    __syncthreads();
    f32x4 acc[4];
    #pragma unroll
    for (int mt=0;mt<4;mt++) acc[mt]=(f32x4){0,0,0,0};
    // ---- ks0 conv
    {
        int so = colp*64 + ((g ^ (colp&7))<<3);
        bf16x8 Bh = *reinterpret_cast<const bf16x8*>(sh_+so);
        bf16x8 Bl = *reinterpret_cast<const bf16x8*>(sl_+so);
        #pragma unroll
        for (int mt=0;mt<4;mt++){
            acc[mt]=MFMA16(cA0[mt][0],Bh,acc[mt],0,0,0);
            acc[mt]=MFMA16(cA0[mt][0],Bl,acc[mt],0,0,0);
            acc[mt]=MFMA16(cA0[mt][1],Bh,acc[mt],0,0,0);
        }
    }
    // ---- issue ks1 loads
    bf16x8 cA1[4][2], zA1[4][2], tB1[2];
    #pragma unroll
    for (int mt=0;mt<4;mt++){
        size_t fo = (size_t)(((L*2+1)*4+mt)*64 + lane)*8;
        cA1[mt][0] = *reinterpret_cast<const bf16x8*>(cfh+fo);
        cA1[mt][1] = *reinterpret_cast<const bf16x8*>(cfl+fo);
        size_t ao = (((size_t)h*64 + mt*16+(lane&15))*64) + 32 + (g<<3);
        zA1[mt][0] = *reinterpret_cast<const bf16x8*>(zh+ao);
        zA1[mt][1] = *reinterpret_cast<const bf16x8*>(zl+ao);
    }
    {
        size_t bo = ((size_t)(wt*2+1)*64 + lane)*8;
        tB1[0] = *reinterpret_cast<const bf16x8*>(t2h+bo);
        tB1[1] = *reinterpret_cast<const bf16x8*>(t2l+bo);
    }
    // ---- ks0 spectral
    #pragma unroll
    for (int mt=0;mt<4;mt++){
        acc[mt]=MFMA16(zA0[mt][0],tB0[0],acc[mt],0,0,0);
        acc[mt]=MFMA16(zA0[mt][0],tB0[1],acc[mt],0,0,0);
        acc[mt]=MFMA16(zA0[mt][1],tB0[0],acc[mt],0,0,0);
    }
    // ---- ks1 conv
    {
        int so = colp*64 + (((4+g) ^ (colp&7))<<3);
        bf16x8 Bh = *reinterpret_cast<const bf16x8*>(sh_+so);
        bf16x8 Bl = *reinterpret_cast<const bf16x8*>(sl_+so);
        #pragma unroll
        for (int mt=0;mt<4;mt++){
            acc[mt]=MFMA16(cA1[mt][0],Bh,acc[mt],0,0,0);
            acc[mt]=MFMA16(cA1[mt][0],Bl,acc[mt],0,0,0);
            acc[mt]=MFMA16(cA1[mt][1],Bh,acc[mt],0,0,0);
        }
    }
    // ---- ks1 spectral
    #pragma unroll
    for (int mt=0;mt<4;mt++){
        acc[mt]=MFMA16(zA1[mt][0],tB1[0],acc[mt],0,0,0);
        acc[mt]=MFMA16(zA1[mt][0],tB1[1],acc[mt],0,0,0);
        acc[mt]=MFMA16(zA1[mt][1],tB1[0],acc[mt],0,0,0);
    }
    // ---- epilogue: tanh+split into padded LDS, then coalesced stores
    #pragma unroll
    for (int mt=0;mt<4;mt++){
        float4 cbv = *reinterpret_cast<const float4*>(cb + mt*16 + (g<<2));
        float cba[4] = {cbv.x, cbv.y, cbv.z, cbv.w};
        #pragma unroll
        for (int rg=0;rg<4;rg++){
            int o = mt*16 + (g<<2) + rg;
            float val = tanhfast(acc[mt][rg] + cba[rg]);
            u16 hh,ll; bsplit(val,hh,ll);
            so_[o*68 + colp] = (unsigned)hh | ((unsigned)ll<<16);
        }
    }
    __syncthreads();
    {
        int o = t>>2, p0 = (t&3)<<4;
        const uint4* sp = reinterpret_cast<const uint4*>(so_ + o*68 + p0);
        uint4 u0 = sp[0], u1 = sp[1], u2 = sp[2], u3 = sp[3];
        us8 h0, h1, l0, l1;
        h0[0]=(u16)u0.x; l0[0]=(u16)(u0.x>>16);
        h0[1]=(u16)u0.y; l0[1]=(u16)(u0.y>>16);
        h0[2]=(u16)u0.z; l0[2]=(u16)(u0.z>>16);
        h0[3]=(u16)u0.w; l0[3]=(u16)(u0.w>>16);
        h0[4]=(u16)u1.x; l0[4]=(u16)(u1.x>>16);
        h0[5]=(u16)u1.y; l0[5]=(u16)(u1.y>>16);
        h0[6]=(u16)u1.z; l0[6]=(u16)(u1.z>>16);
        h0[7]=(u16)u1.w; l0[7]=(u16)(u1.w>>16);
        h1[0]=(u16)u2.x; l1[0]=(u16)(u2.x>>16);
        h1[1]=(u16)u2.y; l1[1]=(u16)(u2.y>>16);
        h1[2]=(u16)u2.z; l1[2]=(u16)(u2.z>>16);
        h1[3]=(u16)u2.w; l1[3]=(u16)(u2.w>>16);
        h1[4]=(u16)u3.x; l1[4]=(u16)(u3.x>>16);
        h1[5]=(u16)u3.y; l1[5]=(u16)(u3.y>>16);
        h1[6]=(u16)u3.z; l1[6]=(u16)(u3.z>>16);
        h1[7]=(u16)u3.w; l1[7]=(u16)(u3.w>>16);
        size_t go = (size_t)o*NP + gbase + p0;
        *(us8*)(vh+go)   = h0;
        *(us8*)(vh+go+8) = h1;
        *(us8*)(vl+go)   = l0;
        *(us8*)(vl+go+8) = l1;
    }
}

// ================= FC1+FC2 (XCD swizzle) =================
__global__ __launch_bounds__(256) void k_fc12(const u16* __restrict__ vh, const u16* __restrict__ vl,
    const char* __restrict__ wsb, const float* __restrict__ b1,
    const float* __restrict__ w2, const float* __restrict__ b2, float* __restrict__ out){
    __shared__ u16 sh_[4096];
    __shared__ u16 sl_[4096];
    int bid = ((blockIdx.x & 7) << 9) | (blockIdx.x >> 3);   // 4096 = 8*512 chunked
    int t = threadIdx.x, lane = t&63, wv = t>>6;
    size_t pb = (size_t)bid*64;
    {
        int c = t>>2, p0=(t&3)<<4;
        short8 a0 = *(const short8*)(vh + (size_t)c*NP + pb + p0);
        short8 a1 = *(const short8*)(vh + (size_t)c*NP + pb + p0+8);
        short8 b0 = *(const short8*)(vl + (size_t)c*NP + pb + p0);
        short8 b1 = *(const short8*)(vl + (size_t)c*NP + pb + p0+8);
        #pragma unroll
        for (int e=0;e<8;e++){
            sh_[(p0+e)*64 + SWZ(c,p0+e)] = (u16)a0[e];
            sh_[(p0+8+e)*64 + SWZ(c,p0+8+e)] = (u16)a1[e];
            sl_[(p0+e)*64 + SWZ(c,p0+e)] = (u16)b0[e];
            sl_[(p0+8+e)*64 + SWZ(c,p0+8+e)] = (u16)b1[e];
        }
    }
    __syncthreads();
    f32x4 acc[8];
    #pragma unroll
    for (int mt=0;mt<8;mt++) acc[mt]=(f32x4){0,0,0,0};
    int colp = wv*16 + (lane&15);
    int g = lane>>4;
    const u16* f1h=(const u16*)(wsb+F1H); const u16* f1l=(const u16*)(wsb+F1L);
    #pragma unroll
    for (int ks=0;ks<2;ks++){
        bf16x8 A[8][2];
        #pragma unroll
        for (int mt=0;mt<8;mt++){
            size_t fo = (size_t)((ks*8+mt)*64 + lane)*8;
            A[mt][0] = *reinterpret_cast<const bf16x8*>(f1h+fo);
            A[mt][1] = *reinterpret_cast<const bf16x8*>(f1l+fo);
        }
        int o8 = ks*4+g;
        int so = colp*64 + ((o8 ^ (colp&7))<<3);
        bf16x8 Bh = *reinterpret_cast<const bf16x8*>(sh_+so);
        bf16x8 Bl = *reinterpret_cast<const bf16x8*>(sl_+so);
        #pragma unroll
        for (int mt=0;mt<8;mt++){
            acc[mt]=MFMA16(A[mt][0],Bh,acc[mt],0,0,0);
            acc[mt]=MFMA16(A[mt][0],Bl,acc[mt],0,0,0);
            acc[mt]=MFMA16(A[mt][1],Bh,acc[mt],0,0,0);
        }
    }
    float s = 0.f;
    #pragma unroll
    for (int mt=0;mt<8;mt++)
        #pragma unroll
        for (int rg=0;rg<4;rg++){
            int f = mt*16 + (g<<2) + rg;
            s += w2[f] * tanhfast(acc[mt][rg] + b1[f]);
        }
    s += __shfl_xor(s, 16);
    s += __shfl_xor(s, 32);
    if (lane < 16) out[pb + wv*16 + lane] = s + b2[0];
}

extern "C" void kernel_launch(void* const* d_in, const int* in_sizes, int n_in,
                              void* d_out, int out_size, void* d_ws, size_t ws_size,
                              hipStream_t stream) {
    const float* x     = (const float*)d_in[0];
    const float* fc0w  = (const float*)d_in[1];
    const float* fc0b  = (const float*)d_in[2];
    const float* sw1r  = (const float*)d_in[3];
    const float* sw1i  = (const float*)d_in[4];
    const float* sw2r  = (const float*)d_in[5];
    const float* sw2i  = (const float*)d_in[6];
    const float* convw = (const float*)d_in[7];
    const float* convb = (const float*)d_in[8];
    const float* fc1w  = (const float*)d_in[9];
    const float* fc1b  = (const float*)d_in[10];
    const float* fc2w  = (const float*)d_in[11];
    const float* fc2b  = (const float*)d_in[12];
    char* wsb = (char*)d_ws;
    float* out = (float*)d_out;

    u16* twh = (u16*)(wsb+TWH); u16* twl = (u16*)(wsb+TWL);
    u16* xwh = (u16*)(wsb+XWH); u16* xwl = (u16*)(wsb+XWL);
    float* xfP = (float*)(wsb+XFP);
    float* ypart = (float*)(wsb+YPART);
    u16* zh = (u16*)(wsb+ZH); u16* zl = (u16*)(wsb+ZL);
    u16* vh = (u16*)(wsb+VH); u16* vl = (u16*)(wsb+VL);

    k_setup<<<544, 256, 0, stream>>>(wsb, convw, fc1w);
    k_fc0<<<256, 256, 0, stream>>>(x, fc0w, fc0b, vh, vl);
    for (int L = 0; L < 4; ++L){
        size_t so = (size_t)L * 64 * 64 * 400;
        k_f1<<<256, 256, 0, stream>>>(vh, vl, twh, twl, xwh, xwl);
        k_f2<<<120, 256, 0, stream>>>(wsb, xfP);
        k_mix<<<256, 256, 0, stream>>>(sw1r+so, sw1i+so, sw2r+so, sw2i+so, xfP, ypart);
        k_mixred<<<320, 256, 0, stream>>>(ypart, wsb);
        k_i1<<<320, 128, 0, stream>>>(wsb, zh, zl);
        k_sct<<<4096, 256, 0, stream>>>(vh, vl, wsb, L, convb + (size_t)L*64, zh, zl);
    }
    k_fc12<<<4096, 256, 0, stream>>>(vh, vl, wsb, fc1b, fc2w, fc2b, out);
}